// Round 12
// baseline (1564.590 us; speedup 1.0000x reference)
//
#include <hip/hip_runtime.h>

#define LEAKF (1.0f/3.0f)
#define BN_EPS 1e-4f

// ---------------- hash table (open addressing, linear probe) ----------------
__device__ __forceinline__ unsigned hmix(int key) {
    unsigned h = (unsigned)key * 2654435761u;
    h ^= h >> 15;
    return h;
}

__device__ __forceinline__ int hlookup(const int* __restrict__ hk,
                                       const int* __restrict__ hv,
                                       int mask, int key) {
    unsigned h = hmix(key) & (unsigned)mask;
    while (true) {
        int k = hk[h];
        if (k == key) return hv[h];
        if (k == -1) return -1;
        h = (h + 1) & (unsigned)mask;
    }
}

__device__ __forceinline__ float bnl(float v, float s, float h) {
    v = v * s + h;
    return v > 0.f ? v : v * LEAKF;
}

// ---------------- fused hash + bitmap build (4 segments) ----------------
__global__ __launch_bounds__(256) void build_hash_bm_all(
    int B0, int B1, int B2,
    int N0, const int* __restrict__ c0, int* __restrict__ hk0, int* __restrict__ hv0,
    int m0, unsigned* __restrict__ bm0,
    int N1, const int* __restrict__ c1, int* __restrict__ hk1, int* __restrict__ hv1,
    int m1, unsigned* __restrict__ bm1,
    int N2, const int* __restrict__ c2, int* __restrict__ hk2, int* __restrict__ hv2,
    int m2, unsigned* __restrict__ bm2,
    int N3, const int* __restrict__ c3, int* __restrict__ hk3, int* __restrict__ hv3,
    int m3) {
    const int* coords; int* hk; int* hv; unsigned* bm; int mask, S, N, i;
    int b = blockIdx.x;
    if (b < B0)           { coords = c0; hk = hk0; hv = hv0; bm = bm0; mask = m0; S = 512; N = N0; i = b * 256 + threadIdx.x; }
    else if (b < B0 + B1) { coords = c1; hk = hk1; hv = hv1; bm = bm1; mask = m1; S = 256; N = N1; i = (b - B0) * 256 + threadIdx.x; }
    else if (b < B0 + B1 + B2) { coords = c2; hk = hk2; hv = hv2; bm = bm2; mask = m2; S = 128; N = N2; i = (b - B0 - B1) * 256 + threadIdx.x; }
    else                  { coords = c3; hk = hk3; hv = hv3; bm = nullptr; mask = m3; S = 32; N = N3; i = (b - B0 - B1 - B2) * 256 + threadIdx.x; }
    if (i >= N) return;
    int key = (coords[3 * i] * S + coords[3 * i + 1]) * S + coords[3 * i + 2];
    if (bm) atomicOr(&bm[key >> 5], 1u << (key & 31));
    unsigned h = hmix(key) & (unsigned)mask;
    while (true) {
        int old = atomicCAS(&hk[h], -1, key);
        if (old == -1 || old == key) { hv[h] = i; break; }
        h = (h + 1) & (unsigned)mask;
    }
}

// ---------------- bitmap-based submanifold rulebook (2 segments) ----------------
__global__ __launch_bounds__(256) void rb_sub_bm(
    int B1,
    int N1, const int* __restrict__ c1, const unsigned* __restrict__ bm1,
    const int* __restrict__ hk1, const int* __restrict__ hv1, int m1,
    int2* __restrict__ rb1, int* __restrict__ cnt1, int cap1,
    int N2, const int* __restrict__ c2, const unsigned* __restrict__ bm2,
    const int* __restrict__ hk2, const int* __restrict__ hv2, int m2,
    int2* __restrict__ rb2, int* __restrict__ cnt2, int cap2) {
    __shared__ int lcnt[27];
    __shared__ int lbase[27];
    int tid = threadIdx.x;
    if (tid < 27) lcnt[tid] = 0;
    __syncthreads();
    const int* coords; const unsigned* bm; const int* hk; const int* hv;
    int mask, S, N, t; int2* pairs; int* counts; int cap;
    if (blockIdx.x < B1) {
        coords = c1; bm = bm1; hk = hk1; hv = hv1; mask = m1; S = 256; N = N1;
        pairs = rb1; counts = cnt1; cap = cap1; t = blockIdx.x * 256 + tid;
    } else {
        coords = c2; bm = bm2; hk = hk2; hv = hv2; mask = m2; S = 128; N = N2;
        pairs = rb2; counts = cnt2; cap = cap2; t = (blockIdx.x - B1) * 256 + tid;
    }
    unsigned bits = 0;
    int m = 0, kmin = 0, z = 0, dx = 0, dy = 0;
    int rk[3], ix[3];
    if (t < N * 9) {
        m = t / 9;
        int od = t - m * 9;
        dx = od / 3 - 1;
        dy = od - (od / 3) * 3 - 1;
        int x = coords[3 * m] + dx;
        int y = coords[3 * m + 1] + dy;
        z = coords[3 * m + 2];
        if ((unsigned)x < (unsigned)S && (unsigned)y < (unsigned)S) {
            int zmin = z - 1 < 0 ? 0 : z - 1;
            int zmax = z + 1 > S - 1 ? S - 1 : z + 1;
            kmin = (x * S + y) * S + zmin;
            int wi = kmin >> 5, sh = kmin & 31, nb = zmax - zmin + 1;
            unsigned long long w =
                ((unsigned long long)bm[wi + 1] << 32) | (unsigned long long)bm[wi];
            bits = (unsigned)((w >> sh) & ((1u << nb) - 1u));
            if (dx == 0 && dy == 0) bits &= ~(1u << (z - zmin));  // drop center
            unsigned tmp = bits;
            int nf = 0;
            while (tmp) {
                int bb = __ffs(tmp) - 1;
                tmp &= tmp - 1;
                ix[nf] = hlookup(hk, hv, mask, kmin + bb);
                int dz = (kmin & (S - 1)) + bb - z;
                int k = (dx + 1) * 9 + (dy + 1) * 3 + (dz + 1);
                rk[nf] = atomicAdd(&lcnt[k], 1);
                nf++;
            }
        }
    }
    __syncthreads();
    if (tid < 27 && lcnt[tid] > 0) lbase[tid] = atomicAdd(&counts[tid], lcnt[tid]);
    __syncthreads();
    {
        unsigned tmp = bits;
        int j = 0;
        while (tmp) {
            int bb = __ffs(tmp) - 1;
            tmp &= tmp - 1;
            int dz = (kmin & (S - 1)) + bb - z;
            int k = (dx + 1) * 9 + (dy + 1) * 3 + (dz + 1);
            int p = lbase[k] + rk[j];
            if (p < cap) pairs[(size_t)k * cap + p] = make_int2(m, ix[j]);
            j++;
        }
    }
}

// ---------------- fused down-conv rulebooks (3 segments) ----------------
__global__ __launch_bounds__(256) void rb_down_all(
    int B1, int B2,
    int N0, const int* __restrict__ c0, const int* __restrict__ hk1,
    const int* __restrict__ hv1, int m1, int2* __restrict__ rbD1,
    int* __restrict__ cntD1, int capD1,
    int N1, const int* __restrict__ c1, const int* __restrict__ hk2,
    const int* __restrict__ hv2, int m2, int2* __restrict__ rbD2,
    int* __restrict__ cntD2, int capD2,
    int N2, const int* __restrict__ c2, const int* __restrict__ hk3,
    const int* __restrict__ hv3, int m3, int2* __restrict__ rbD3,
    int* __restrict__ cntD3, int capD3) {
    __shared__ int lcnt[64];
    __shared__ int lbase[64];
    int tid = threadIdx.x;
    const int* cin; const int* hk; const int* hv;
    int mask, Sout, s, Nin, i; int2* pairs; int* counts; int cap;
    int b = blockIdx.x;
    if (b < B1) {
        cin = c0; hk = hk1; hv = hv1; mask = m1; Sout = 256; s = 2; Nin = N0;
        pairs = rbD1; counts = cntD1; cap = capD1; i = b * 256 + tid;
    } else if (b < B1 + B2) {
        cin = c1; hk = hk2; hv = hv2; mask = m2; Sout = 128; s = 2; Nin = N1;
        pairs = rbD2; counts = cntD2; cap = capD2; i = (b - B1) * 256 + tid;
    } else {
        cin = c2; hk = hk3; hv = hv3; mask = m3; Sout = 32; s = 4; Nin = N2;
        pairs = rbD3; counts = cntD3; cap = capD3; i = (b - B1 - B2) * 256 + tid;
    }
    int K3 = s * s * s;
    if (tid < K3) lcnt[tid] = 0;
    __syncthreads();
    int k = -1, m = -1, rank = 0;
    if (i < Nin) {
        int x = cin[3 * i], y = cin[3 * i + 1], z = cin[3 * i + 2];
        k = ((x % s) * s + (y % s)) * s + (z % s);
        int key = ((x / s) * Sout + (y / s)) * Sout + (z / s);
        m = hlookup(hk, hv, mask, key);
        rank = atomicAdd(&lcnt[k], 1);
    }
    __syncthreads();
    if (tid < K3 && lcnt[tid] > 0) lbase[tid] = atomicAdd(&counts[tid], lcnt[tid]);
    __syncthreads();
    if (i < Nin) {
        int p = lbase[k] + rank;
        if (p < cap) pairs[(size_t)k * cap + p] = make_int2(m, i);
    }
}

// ---- initial 7^3 conv probe: thread per (site,dx); 7 independent dy window loads ----
__global__ __launch_bounds__(256) void init_probe(
    int total, int chunk, const int* __restrict__ c0, const unsigned* __restrict__ bm,
    const int* __restrict__ hk, const int* __restrict__ hv, int mask,
    int2* __restrict__ pairs, int* __restrict__ pcount, int cap) {
    __shared__ int lcnt, lbase;
    int tid = threadIdx.x;
    if (tid == 0) lcnt = 0;
    __syncthreads();
    int b = blockIdx.x;
    int nb = (b & 7) * chunk + (b >> 3);
    int t = nb * 256 + tid;
    unsigned bitsArr[7];
    int kminArr[7];
#pragma unroll
    for (int j = 0; j < 7; j++) { bitsArr[j] = 0; kminArr[j] = 0; }
    int m = -1, z = 0, dx = 0, rank = 0, found = 0;
    if (t < total) {
        m = t / 7;
        dx = t - m * 7 - 3;
        int x = c0[3 * m] + dx;
        int cy = c0[3 * m + 1];
        z = c0[3 * m + 2];
        if ((unsigned)x < 512u) {
            int zmin = z - 3 < 0 ? 0 : z - 3;
            int zmax = z + 3 > 511 ? 511 : z + 3;
            int nbits = zmax - zmin + 1;
#pragma unroll
            for (int j = 0; j < 7; j++) {
                int y = cy + j - 3;
                if ((unsigned)y < 512u) {
                    int kmin = (x * 512 + y) * 512 + zmin;
                    kminArr[j] = kmin;
                    int wi = kmin >> 5, sh = kmin & 31;
                    unsigned long long w =
                        ((unsigned long long)bm[wi + 1] << 32) | (unsigned long long)bm[wi];
                    unsigned bits = (unsigned)((w >> sh) & ((1u << nbits) - 1u));
                    if (dx == 0 && j == 3) bits &= ~(1u << (z - zmin));
                    bitsArr[j] = bits;
                    found += __popc(bits);
                }
            }
        }
    }
    if (found) rank = atomicAdd(&lcnt, found);
    __syncthreads();
    if (tid == 0 && lcnt > 0) lbase = atomicAdd(pcount, lcnt);
    __syncthreads();
    if (found) {
        int p = lbase + rank;
#pragma unroll
        for (int j = 0; j < 7; j++) {
            unsigned bits = bitsArr[j];
            while (bits) {
                int b2 = __ffs(bits) - 1;
                bits &= bits - 1;
                int nkey = kminArr[j] + b2;
                int idx = hlookup(hk, hv, mask, nkey);
                int dz = (kminArr[j] & 511) + b2 - z;
                int k = (dx + 3) * 49 + j * 7 + (dz + 3);
                if (p < cap) pairs[p] = make_int2(m, idx | (k << 17));
                p++;
            }
        }
    }
}

__global__ __launch_bounds__(256) void init_center(
    int N0, const float* __restrict__ f0, const float* __restrict__ W,
    float* __restrict__ out) {
    int t = blockIdx.x * 256 + threadIdx.x;
    if (t >= N0 * 64) return;
    int m = t >> 6, co = t & 63;
    out[t] = f0[m] * W[171 * 64 + co];
}

__global__ __launch_bounds__(256) void init_apply(
    const int2* __restrict__ pairs, const int* __restrict__ pcount, int cap,
    const float* __restrict__ f0, const float* __restrict__ W,
    float* __restrict__ out) {
    int P = min(*pcount, cap);
    int t = blockIdx.x * 256 + threadIdx.x;
    if (t >= P * 64) return;
    int p = t >> 6, co = t & 63;
    int2 pr = pairs[p];
    int idx = pr.y & 0x1FFFF, k = pr.y >> 17;
    atomicAdd(&out[(size_t)pr.x * 64 + co], f0[idx] * W[k * 64 + co]);
}

// ---------------- center GEMM: thread owns 2 cos (co, co+32) ----------------
template <int C, int TS, bool BNF>
__global__ __launch_bounds__(256) void center_gemm(
    int N, const float* __restrict__ inF, const float* __restrict__ Wc,
    float* __restrict__ out, const float* __restrict__ scp,
    const float* __restrict__ shp) {
    constexpr int C4 = C / 4;
    constexpr int SP = TS / 8;
    __shared__ float sW[C * 64];
    __shared__ float4 sRow[TS * C4];
    int tid = threadIdx.x;
    int t0 = blockIdx.x * TS;
    int co0 = blockIdx.y << 6;
    for (int e = tid; e < C * 16; e += 256) {
        int ci = e >> 4, c4 = e & 15;
        ((float4*)sW)[e] = *(const float4*)(Wc + (size_t)ci * C + co0 + c4 * 4);
    }
    for (int e = tid; e < TS * C4; e += 256) {
        int p = e / C4, c4 = e - p * C4;
        float4 v = make_float4(0.f, 0.f, 0.f, 0.f);
        if (t0 + p < N) {
            v = ((const float4*)inF)[(size_t)(t0 + p) * C4 + c4];
            if (BNF) {
                float4 s4 = ((const float4*)scp)[c4];
                float4 h4 = ((const float4*)shp)[c4];
                v.x = bnl(v.x, s4.x, h4.x);
                v.y = bnl(v.y, s4.y, h4.y);
                v.z = bnl(v.z, s4.z, h4.z);
                v.w = bnl(v.w, s4.w, h4.w);
            }
        }
        sRow[e] = v;
    }
    __syncthreads();
    int co = tid & 31, sg = tid >> 5;
    float accA[SP], accB[SP];
#pragma unroll
    for (int j = 0; j < SP; j++) { accA[j] = 0.f; accB[j] = 0.f; }
    for (int c4 = 0; c4 < C4; c4++) {
        float a0 = sW[(c4 * 4 + 0) * 64 + co];
        float a1 = sW[(c4 * 4 + 1) * 64 + co];
        float a2 = sW[(c4 * 4 + 2) * 64 + co];
        float a3 = sW[(c4 * 4 + 3) * 64 + co];
        float b0 = sW[(c4 * 4 + 0) * 64 + co + 32];
        float b1 = sW[(c4 * 4 + 1) * 64 + co + 32];
        float b2 = sW[(c4 * 4 + 2) * 64 + co + 32];
        float b3 = sW[(c4 * 4 + 3) * 64 + co + 32];
#pragma unroll
        for (int j = 0; j < SP; j++) {
            float4 r = sRow[(sg * SP + j) * C4 + c4];
            accA[j] += r.x * a0 + r.y * a1 + r.z * a2 + r.w * a3;
            accB[j] += r.x * b0 + r.y * b1 + r.z * b2 + r.w * b3;
        }
    }
#pragma unroll
    for (int j = 0; j < SP; j++) {
        int p = sg * SP + j;
        if (t0 + p < N) {
            out[(size_t)(t0 + p) * C + co0 + co] = accA[j];
            out[(size_t)(t0 + p) * C + co0 + co + 32] = accB[j];
        }
    }
}

// ---- pair GEMM (CIN=64 path); XCD-swizzled; co-slab loop.
// MODE: 0=raw, 1=bn+lrelu, 2=lrelu(inF+inF2). ----
template <int CIN, int P, int MODE>
__global__ __launch_bounds__(256) void pair_gemm(
    const float* __restrict__ inF, const float* __restrict__ inF2,
    const float* __restrict__ W, float* __restrict__ out,
    const int2* __restrict__ pairs, const int* __restrict__ counts,
    int cap, int chunksPerK, int totalNb, int COUT, int nslab,
    const float* __restrict__ scp, const float* __restrict__ shp) {
    constexpr int C4 = CIN / 4;
    constexpr int SP = P / 8;
    __shared__ float sW[CIN * 64];
    __shared__ float4 sRow[P * C4];
    __shared__ int sM[P];
    __shared__ int sIdx[P];
    int b = blockIdx.x;
    int nb = (b & 7) * (gridDim.x >> 3) + (b >> 3);
    if (nb >= totalNb) return;
    int k = nb / chunksPerK;
    int chunk = nb - k * chunksPerK;
    int cnt = min(counts[k], cap);
    int base = chunk * P;
    if (base >= cnt) return;
    int Pact = min(P, cnt - base);
    int tid = threadIdx.x;
    if (tid < P) {
        if (tid < Pact) {
            int2 pr = pairs[(size_t)k * cap + base + tid];
            sM[tid] = pr.x;
            sIdx[tid] = pr.y;
        } else {
            sM[tid] = -1;
            sIdx[tid] = 0;
        }
    }
    __syncthreads();
    int co = tid & 31, sg = tid >> 5;
    for (int s = 0; s < nslab; s++) {
        int co0 = s << 6;
        if (s > 0) __syncthreads();
        const float* gW = W + (size_t)k * CIN * COUT + co0;
        for (int e = tid; e < CIN * 16; e += 256) {
            int ci = e >> 4, c4 = e & 15;
            ((float4*)sW)[e] = *(const float4*)(gW + (size_t)ci * COUT + c4 * 4);
        }
        if (s == 0) {
            for (int e = tid; e < P * C4; e += 256) {
                int p = e / C4, c4 = e - p * C4;
                float4 v = make_float4(0.f, 0.f, 0.f, 0.f);
                if (p < Pact) {
                    v = ((const float4*)inF)[(size_t)sIdx[p] * C4 + c4];
                    if (MODE == 1) {
                        float4 s4 = ((const float4*)scp)[c4];
                        float4 h4 = ((const float4*)shp)[c4];
                        v.x = bnl(v.x, s4.x, h4.x);
                        v.y = bnl(v.y, s4.y, h4.y);
                        v.z = bnl(v.z, s4.z, h4.z);
                        v.w = bnl(v.w, s4.w, h4.w);
                    } else if (MODE == 2) {
                        float4 u = ((const float4*)inF2)[(size_t)sIdx[p] * C4 + c4];
                        v.x += u.x; v.y += u.y; v.z += u.z; v.w += u.w;
                        v.x = v.x > 0.f ? v.x : v.x * LEAKF;
                        v.y = v.y > 0.f ? v.y : v.y * LEAKF;
                        v.z = v.z > 0.f ? v.z : v.z * LEAKF;
                        v.w = v.w > 0.f ? v.w : v.w * LEAKF;
                    }
                }
                sRow[e] = v;
            }
        }
        __syncthreads();
        float accA[SP], accB[SP];
#pragma unroll
        for (int j = 0; j < SP; j++) { accA[j] = 0.f; accB[j] = 0.f; }
        for (int c4 = 0; c4 < C4; c4++) {
            float a0 = sW[(c4 * 4 + 0) * 64 + co];
            float a1 = sW[(c4 * 4 + 1) * 64 + co];
            float a2 = sW[(c4 * 4 + 2) * 64 + co];
            float a3 = sW[(c4 * 4 + 3) * 64 + co];
            float b0 = sW[(c4 * 4 + 0) * 64 + co + 32];
            float b1 = sW[(c4 * 4 + 1) * 64 + co + 32];
            float b2 = sW[(c4 * 4 + 2) * 64 + co + 32];
            float b3 = sW[(c4 * 4 + 3) * 64 + co + 32];
#pragma unroll
            for (int j = 0; j < SP; j++) {
                float4 r = sRow[(sg * SP + j) * C4 + c4];
                accA[j] += r.x * a0 + r.y * a1 + r.z * a2 + r.w * a3;
                accB[j] += r.x * b0 + r.y * b1 + r.z * b2 + r.w * b3;
            }
        }
#pragma unroll
        for (int j = 0; j < SP; j++) {
            int p = sg * SP + j;
            if (p < Pact) {
                atomicAdd(&out[(size_t)sM[p] * COUT + co0 + co], accA[j]);
                atomicAdd(&out[(size_t)sM[p] * COUT + co0 + co + 32], accB[j]);
            }
        }
    }
}

// ---- pair GEMM, CIN=128 path: 32-wide co-slabs, P=16 -> ~25 KB LDS, high occupancy.
// MODE: 1=bn+lrelu, 2=lrelu(inF+inF2), 0=raw. ----
template <int CIN, int P, int MODE>
__global__ __launch_bounds__(256) void pair_gemm32(
    const float* __restrict__ inF, const float* __restrict__ inF2,
    const float* __restrict__ W, float* __restrict__ out,
    const int2* __restrict__ pairs, const int* __restrict__ counts,
    int cap, int chunksPerK, int totalNb, int COUT, int nslab,
    const float* __restrict__ scp, const float* __restrict__ shp) {
    constexpr int C4 = CIN / 4;
    constexpr int SP = P / 8;
    __shared__ float sW[CIN * 32];
    __shared__ float4 sRow[P * C4];
    __shared__ int sM[P];
    __shared__ int sIdx[P];
    int b = blockIdx.x;
    int nb = (b & 7) * (gridDim.x >> 3) + (b >> 3);
    if (nb >= totalNb) return;
    int k = nb / chunksPerK;
    int chunk = nb - k * chunksPerK;
    int cnt = min(counts[k], cap);
    int base = chunk * P;
    if (base >= cnt) return;
    int Pact = min(P, cnt - base);
    int tid = threadIdx.x;
    if (tid < P) {
        if (tid < Pact) {
            int2 pr = pairs[(size_t)k * cap + base + tid];
            sM[tid] = pr.x;
            sIdx[tid] = pr.y;
        } else {
            sM[tid] = -1;
            sIdx[tid] = 0;
        }
    }
    __syncthreads();
    int co = tid & 31, sg = tid >> 5;
    for (int s = 0; s < nslab; s++) {
        int co0 = s << 5;
        if (s > 0) __syncthreads();
        const float* gW = W + (size_t)k * CIN * COUT + co0;
        for (int e = tid; e < CIN * 8; e += 256) {
            int ci = e >> 3, cq = e & 7;
            ((float4*)sW)[e] = *(const float4*)(gW + (size_t)ci * COUT + cq * 4);
        }
        if (s == 0) {
            for (int e = tid; e < P * C4; e += 256) {
                int p = e / C4, c4 = e - p * C4;
                float4 v = make_float4(0.f, 0.f, 0.f, 0.f);
                if (p < Pact) {
                    v = ((const float4*)inF)[(size_t)sIdx[p] * C4 + c4];
                    if (MODE == 1) {
                        float4 s4 = ((const float4*)scp)[c4];
                        float4 h4 = ((const float4*)shp)[c4];
                        v.x = bnl(v.x, s4.x, h4.x);
                        v.y = bnl(v.y, s4.y, h4.y);
                        v.z = bnl(v.z, s4.z, h4.z);
                        v.w = bnl(v.w, s4.w, h4.w);
                    } else if (MODE == 2) {
                        float4 u = ((const float4*)inF2)[(size_t)sIdx[p] * C4 + c4];
                        v.x += u.x; v.y += u.y; v.z += u.z; v.w += u.w;
                        v.x = v.x > 0.f ? v.x : v.x * LEAKF;
                        v.y = v.y > 0.f ? v.y : v.y * LEAKF;
                        v.z = v.z > 0.f ? v.z : v.z * LEAKF;
                        v.w = v.w > 0.f ? v.w : v.w * LEAKF;
                    }
                }
                sRow[e] = v;
            }
        }
        __syncthreads();
        float acc[SP];
#pragma unroll
        for (int j = 0; j < SP; j++) acc[j] = 0.f;
        for (int c4 = 0; c4 < C4; c4++) {
            float w0 = sW[(c4 * 4 + 0) * 32 + co];
            float w1 = sW[(c4 * 4 + 1) * 32 + co];
            float w2 = sW[(c4 * 4 + 2) * 32 + co];
            float w3 = sW[(c4 * 4 + 3) * 32 + co];
#pragma unroll
            for (int j = 0; j < SP; j++) {
                float4 r = sRow[(sg * SP + j) * C4 + c4];
                acc[j] += r.x * w0 + r.y * w1 + r.z * w2 + r.w * w3;
            }
        }
#pragma unroll
        for (int j = 0; j < SP; j++) {
            int p = sg * SP + j;
            if (p < Pact) atomicAdd(&out[(size_t)sM[p] * COUT + co0 + co], acc[j]);
        }
    }
}

// ---------------- batchnorm: register-accum reduce + last-block finalize ----------------
__global__ __launch_bounds__(256) void bn_reduce_fin(
    const float4* __restrict__ X4, int total4, int B4, int C, int Cmask, float invN,
    const float* __restrict__ g, const float* __restrict__ b,
    float* __restrict__ sums, int* __restrict__ done,
    float* __restrict__ sc, float* __restrict__ sh) {
    __shared__ float sS[128];
    __shared__ float sQ[128];
    __shared__ int isLast;
    int tid = threadIdx.x;
    if (tid < C) { sS[tid] = 0.f; sQ[tid] = 0.f; }
    __syncthreads();
    int base4 = blockIdx.x * B4;
    int end4 = min(base4 + B4, total4);
    float s0 = 0.f, s1 = 0.f, s2 = 0.f, s3 = 0.f;
    float q0 = 0.f, q1 = 0.f, q2 = 0.f, q3 = 0.f;
    for (int e4 = base4 + tid; e4 < end4; e4 += 256) {
        float4 v = X4[e4];
        s0 += v.x; q0 += v.x * v.x;
        s1 += v.y; q1 += v.y * v.y;
        s2 += v.z; q2 += v.z * v.z;
        s3 += v.w; q3 += v.w * v.w;
    }
    int c0 = (4 * (base4 + tid)) & Cmask;
    atomicAdd(&sS[c0], s0);               atomicAdd(&sQ[c0], q0);
    atomicAdd(&sS[(c0 + 1) & Cmask], s1); atomicAdd(&sQ[(c0 + 1) & Cmask], q1);
    atomicAdd(&sS[(c0 + 2) & Cmask], s2); atomicAdd(&sQ[(c0 + 2) & Cmask], q2);
    atomicAdd(&sS[(c0 + 3) & Cmask], s3); atomicAdd(&sQ[(c0 + 3) & Cmask], q3);
    __syncthreads();
    if (tid < C) {
        atomicAdd(&sums[tid], sS[tid]);
        atomicAdd(&sums[128 + tid], sQ[tid]);
    }
    __syncthreads();
    if (tid == 0) {
        __threadfence();
        int t = atomicAdd(done, 1);
        isLast = (t == (int)gridDim.x - 1);
    }
    __syncthreads();
    if (isLast) {
        if (tid < C) {
            float v1 = atomicAdd(&sums[tid], 0.0f);
            float v2 = atomicAdd(&sums[128 + tid], 0.0f);
            float mean = v1 * invN;
            float var = v2 * invN - mean * mean;
            float s = g[tid] / sqrtf(var + BN_EPS);
            sc[tid] = s;
            sh[tid] = b[tid] - mean * s;
            sums[tid] = 0.f;
            sums[128 + tid] = 0.f;
        }
        if (tid == 0) *done = 0;
    }
}

// out = lrelu(A + bnl(X))   (float4)
__global__ __launch_bounds__(256) void add_lrelu_bn(const float4* __restrict__ A,
                                                    const float4* __restrict__ X,
                                                    float4* __restrict__ Y, int total4,
                                                    int C4mask,
                                                    const float* __restrict__ scp,
                                                    const float* __restrict__ shp) {
    int e = blockIdx.x * 256 + threadIdx.x;
    if (e >= total4) return;
    int c4 = e & C4mask;
    float4 s4 = ((const float4*)scp)[c4];
    float4 h4 = ((const float4*)shp)[c4];
    float4 a = A[e], x = X[e], v;
    v.x = a.x + bnl(x.x, s4.x, h4.x);
    v.y = a.y + bnl(x.y, s4.y, h4.y);
    v.z = a.z + bnl(x.z, s4.z, h4.z);
    v.w = a.w + bnl(x.w, s4.w, h4.w);
    v.x = v.x > 0.f ? v.x : v.x * LEAKF;
    v.y = v.y > 0.f ? v.y : v.y * LEAKF;
    v.z = v.z > 0.f ? v.z : v.z * LEAKF;
    v.w = v.w > 0.f ? v.w : v.w * LEAKF;
    Y[e] = v;
}

// ---- fused tail: convd4 (bnl on input) -> last-block BN(gd4) + scatter + head ----
__global__ __launch_bounds__(64) void tail_kernel(
    int M, const int* __restrict__ oc, const float* __restrict__ x3,
    const float* __restrict__ W, float* __restrict__ x4,
    const int* __restrict__ hk, const int* __restrict__ hv, int mask,
    const float* __restrict__ scp, const float* __restrict__ shp,
    const float* __restrict__ g4, const float* __restrict__ b4,
    const float* __restrict__ W2, const float* __restrict__ b2,
    const float* __restrict__ W3, const float* __restrict__ b3,
    int* __restrict__ ticket, float* __restrict__ out) {
    __shared__ int sIdx[64];
    __shared__ int sK[64];
    __shared__ int sCount;
    __shared__ int isLast;
    __shared__ float sDense[1024];
    __shared__ float sS[2], sQ[2], ssc[2], ssh[2];
    int m = blockIdx.x, tid = threadIdx.x;
    int cx = oc[3 * m], cy = oc[3 * m + 1], cz = oc[3 * m + 2];
    if (tid == 0) sCount = 0;
    __syncthreads();
    {
        int k = tid;
        int a = k >> 4, b = (k >> 2) & 3, c = k & 3;
        int x = cx * 4 + a, y = cy * 4 + b, z = cz * 4 + c;
        int key = (x * 32 + y) * 32 + z;
        int idx = hlookup(hk, hv, mask, key);
        if (idx >= 0) { int p = atomicAdd(&sCount, 1); sIdx[p] = idx; sK[p] = k; }
    }
    __syncthreads();
    int cnt = sCount;
    float s = scp[tid], h = shp[tid];
    float a0 = 0.f, a1 = 0.f;
    for (int j = 0; j < cnt; j++) {
        int idx = sIdx[j], k = sK[j];
        float f = bnl(x3[(size_t)idx * 64 + tid], s, h);
        const float* wk = W + ((size_t)k * 64 + tid) * 2;
        a0 += f * wk[0];
        a1 += f * wk[1];
    }
    for (int o = 32; o > 0; o >>= 1) {
        a0 += __shfl_down(a0, o);
        a1 += __shfl_down(a1, o);
    }
    if (tid == 0) { x4[2 * m] = a0; x4[2 * m + 1] = a1; }
    __threadfence();
    if (tid == 0) {
        int t = atomicAdd(ticket, 1);
        isLast = (t == (int)gridDim.x - 1);
    }
    __syncthreads();
    if (!isLast) return;
    if (tid < 2) { sS[tid] = 0.f; sQ[tid] = 0.f; }
    for (int i = tid; i < 1024; i += 64) sDense[i] = 0.f;
    __syncthreads();
    float ls = 0.f, lq = 0.f;
    for (int i = tid; i < 2 * M; i += 64) {
        float v = atomicAdd(&x4[i], 0.0f);
        ls += v; lq += v * v;
    }
    atomicAdd(&sS[tid & 1], ls);
    atomicAdd(&sQ[tid & 1], lq);
    __syncthreads();
    if (tid < 2) {
        float mean = sS[tid] / (float)M;
        float var = sQ[tid] / (float)M - mean * mean;
        float sc = g4[tid] / sqrtf(var + BN_EPS);
        ssc[tid] = sc;
        ssh[tid] = b4[tid] - mean * sc;
    }
    __syncthreads();
    for (int i = tid; i < 2 * M; i += 64) {
        int mm = i >> 1, co = i & 1;
        float v = atomicAdd(&x4[i], 0.0f) * ssc[co] + ssh[co];
        v = v > 0.f ? v : v * LEAKF;
        int key = (oc[3 * mm] * 8 + oc[3 * mm + 1]) * 8 + oc[3 * mm + 2];
        sDense[key * 2 + co] = v;
    }
    __syncthreads();
    float h0 = 0.f, h1 = 0.f;
    for (int j = tid; j < 1024; j += 64) {
        int co = j >> 9, k = j & 511;
        float f = sDense[k * 2 + co];
        h0 += f * W2[2 * j];
        h1 += f * W2[2 * j + 1];
    }
    for (int o = 32; o > 0; o >>= 1) {
        h0 += __shfl_down(h0, o);
        h1 += __shfl_down(h1, o);
    }
    if (tid == 0) {
        float v0 = h0 + b2[0];
        float v1 = h1 + b2[1];
        v0 = v0 > 0.f ? v0 : expm1f(v0);
        v1 = v1 > 0.f ? v1 : expm1f(v1);
        float z = v0 * W3[0] + v1 * W3[1] + b3[0];
        out[0] = 1.f / (1.f + expf(-z));
    }
}

// ---------------- host ----------------
extern "C" void kernel_launch(void* const* d_in, const int* in_sizes, int n_in,
                              void* d_out, int out_size, void* d_ws, size_t ws_size,
                              hipStream_t stream) {
    const float* F0    = (const float*)d_in[0];
    const float* Winit = (const float*)d_in[1];
    const float* Wd1   = (const float*)d_in[2];
    const float* gd1   = (const float*)d_in[3];
    const float* bd1   = (const float*)d_in[4];
    const float* W11a  = (const float*)d_in[5];
    const float* g11   = (const float*)d_in[6];
    const float* b11   = (const float*)d_in[7];
    const float* W11b  = (const float*)d_in[8];
    const float* W12a  = (const float*)d_in[9];
    const float* g12   = (const float*)d_in[10];
    const float* b12   = (const float*)d_in[11];
    const float* W12b  = (const float*)d_in[12];
    const float* Wd2   = (const float*)d_in[13];
    const float* gd2   = (const float*)d_in[14];
    const float* bd2   = (const float*)d_in[15];
    const float* W21a  = (const float*)d_in[16];
    const float* g21   = (const float*)d_in[17];
    const float* b21   = (const float*)d_in[18];
    const float* W21b  = (const float*)d_in[19];
    const float* W22a  = (const float*)d_in[20];
    const float* g22   = (const float*)d_in[21];
    const float* b22   = (const float*)d_in[22];
    const float* W22b  = (const float*)d_in[23];
    const float* Wd3   = (const float*)d_in[24];
    const float* gd3   = (const float*)d_in[25];
    const float* bd3   = (const float*)d_in[26];
    const float* Wd4   = (const float*)d_in[27];
    const float* gd4   = (const float*)d_in[28];
    const float* bd4   = (const float*)d_in[29];
    const float* W2    = (const float*)d_in[30];
    const float* b2    = (const float*)d_in[31];
    const float* W3    = (const float*)d_in[32];
    const float* b3    = (const float*)d_in[33];
    const int* c0 = (const int*)d_in[34];
    const int* c1 = (const int*)d_in[35];
    const int* c2 = (const int*)d_in[36];
    const int* c3 = (const int*)d_in[37];
    const int* c4 = (const int*)d_in[38];
    int N0 = in_sizes[34] / 3, N1 = in_sizes[35] / 3, N2 = in_sizes[36] / 3;
    int N3 = in_sizes[37] / 3, N4 = in_sizes[38] / 3;

    // ---- workspace layout ----
    char* base = (char*)d_ws;
    size_t off = 0;
    auto alloc = [&](size_t bytes) -> void* {
        void* p = base + off;
        off = (off + bytes + 255) & ~(size_t)255;
        return p;
    };
    const int CAP0 = 262144, CAP = 131072, CAP3 = 65536;
    size_t hs_off = off;
    int* hk0 = (int*)alloc((size_t)CAP0 * 4);
    int* hv0 = (int*)alloc((size_t)CAP0 * 4);
    int* hk1 = (int*)alloc((size_t)CAP * 4);
    int* hv1 = (int*)alloc((size_t)CAP * 4);
    int* hk2 = (int*)alloc((size_t)CAP * 4);
    int* hv2 = (int*)alloc((size_t)CAP * 4);
    int* hk3 = (int*)alloc((size_t)CAP3 * 4);
    int* hv3 = (int*)alloc((size_t)CAP3 * 4);
    size_t he_off = off;
    size_t zs_off = off;
    float* sums = (float*)alloc(256 * 4);
    float* scb = (float*)alloc(8 * 128 * 4);
    float* shb = (float*)alloc(8 * 128 * 4);
    float* x4 = (float*)alloc(1032 * 4);
    int* counts = (int*)alloc(136 * 4);
    unsigned* bm1 = (unsigned*)alloc((size_t)(524288 + 2) * 4);
    unsigned* bm2 = (unsigned*)alloc((size_t)(65536 + 2) * 4);
    size_t ze_off = off;
    int* cntS1 = counts, *cntS2 = counts + 27, *cntD1 = counts + 54, *cntD2 = counts + 62,
       * cntD3 = counts + 70;
    int* done = counts + 134;
    int* pcount = counts + 135;
    const int CAP_S1 = 1024, CAP_S2 = 4096, CAP_D1 = 8192, CAP_D2 = 8192, CAP_D3 = 1024;
    const int CAPP = 16384;
    int2* pairs0 = (int2*)alloc((size_t)CAPP * 8);
    int2* rbS1 = (int2*)alloc((size_t)27 * CAP_S1 * 8);
    int2* rbS2 = (int2*)alloc((size_t)27 * CAP_S2 * 8);
    int2* rbD1 = (int2*)alloc((size_t)8 * CAP_D1 * 8);
    int2* rbD2 = (int2*)alloc((size_t)8 * CAP_D2 * 8);
    int2* rbD3 = (int2*)alloc((size_t)64 * CAP_D3 * 8);
    size_t relems = (size_t)N0 * 64;
    if ((size_t)N2 * 128 > relems) relems = (size_t)N2 * 128;
    float* R1 = (float*)alloc(relems * 4);
    float* R2 = (float*)alloc(relems * 4);
    float* R3 = (float*)alloc(relems * 4);
    unsigned* bm0 = (unsigned*)R1;   // 16.8 MB, dead before down1

    // ---- consolidated init memsets ----
    hipMemsetAsync(base + hs_off, 0xFF, he_off - hs_off, stream);
    hipMemsetAsync(base + zs_off, 0x00, ze_off - zs_off, stream);
    hipMemsetAsync(bm0, 0x00, (size_t)(1 << 24) + 64, stream);

    int Bh0 = (N0 + 255) / 256, Bh1 = (N1 + 255) / 256, Bh2 = (N2 + 255) / 256,
        Bh3 = (N3 + 255) / 256;
    build_hash_bm_all<<<Bh0 + Bh1 + Bh2 + Bh3, 256, 0, stream>>>(
        Bh0, Bh1, Bh2,
        N0, c0, hk0, hv0, CAP0 - 1, bm0,
        N1, c1, hk1, hv1, CAP - 1, bm1,
        N2, c2, hk2, hv2, CAP - 1, bm2,
        N3, c3, hk3, hv3, CAP3 - 1);
    int Bs1 = (N1 * 9 + 255) / 256, Bs2 = (N2 * 9 + 255) / 256;
    rb_sub_bm<<<Bs1 + Bs2, 256, 0, stream>>>(
        Bs1,
        N1, c1, bm1, hk1, hv1, CAP - 1, rbS1, cntS1, CAP_S1,
        N2, c2, bm2, hk2, hv2, CAP - 1, rbS2, cntS2, CAP_S2);
    rb_down_all<<<Bh0 + Bh1 + Bh2, 256, 0, stream>>>(
        Bh0, Bh1,
        N0, c0, hk1, hv1, CAP - 1, rbD1, cntD1, CAP_D1,
        N1, c1, hk2, hv2, CAP - 1, rbD2, cntD2, CAP_D2,
        N2, c2, hk3, hv3, CAP3 - 1, rbD3, cntD3, CAP_D3);

    auto bnstats = [&](const float* X, int N, int C, const float* g, const float* b,
                       int slot) {
        int total4 = (N * C + 3) >> 2;
        int B4 = 32 * C;
        int grid = (total4 + B4 - 1) / B4;
        bn_reduce_fin<<<grid, 256, 0, stream>>>((const float4*)X, total4, B4, C, C - 1,
                                                1.0f / (float)N, g, b, sums, done,
                                                scb + slot * 128, shb + slot * 128);
    };
    const int CH_S1 = CAP_S1 / 64;    // 16
    const int CH_S2 = CAP_S2 / 16;    // 256 (P=16 path)
    const int CH_D12 = CAP_D1 / 64;   // 128
    const int CH_D3 = CAP_D3 / 16;    // 64  (P=16 path)
    auto sub64 = [&](const float* X, const float* W, float* Y, int slot) {
        if (slot >= 0) {
            center_gemm<64, 64, true><<<dim3((N1 + 63) / 64, 1), 256, 0, stream>>>(
                N1, X, W + 13 * 64 * 64, Y, scb + slot * 128, shb + slot * 128);
            pair_gemm<64, 64, 1><<<27 * CH_S1, 256, 0, stream>>>(
                X, nullptr, W, Y, rbS1, cntS1, CAP_S1, CH_S1, 27 * CH_S1, 64, 1,
                scb + slot * 128, shb + slot * 128);
        } else {
            center_gemm<64, 64, false><<<dim3((N1 + 63) / 64, 1), 256, 0, stream>>>(
                N1, X, W + 13 * 64 * 64, Y, nullptr, nullptr);
            pair_gemm<64, 64, 0><<<27 * CH_S1, 256, 0, stream>>>(
                X, nullptr, W, Y, rbS1, cntS1, CAP_S1, CH_S1, 27 * CH_S1, 64, 1,
                nullptr, nullptr);
        }
    };
    auto sub128 = [&](const float* X, const float* W, float* Y, int slot) {
        if (slot >= 0) {
            center_gemm<128, 48, true><<<dim3((N2 + 47) / 48, 2), 256, 0, stream>>>(
                N2, X, W + 13 * 128 * 128, Y, scb + slot * 128, shb + slot * 128);
            pair_gemm32<128, 16, 1><<<27 * CH_S2, 256, 0, stream>>>(
                X, nullptr, W, Y, rbS2, cntS2, CAP_S2, CH_S2, 27 * CH_S2, 128, 4,
                scb + slot * 128, shb + slot * 128);
        } else {
            center_gemm<128, 48, false><<<dim3((N2 + 47) / 48, 2), 256, 0, stream>>>(
                N2, X, W + 13 * 128 * 128, Y, nullptr, nullptr);
            pair_gemm32<128, 16, 0><<<27 * CH_S2, 256, 0, stream>>>(
                X, nullptr, W, Y, rbS2, cntS2, CAP_S2, CH_S2, 27 * CH_S2, 128, 4,
                nullptr, nullptr);
        }
    };

    // ---- initial conv @512: (site,dx) probe / center / apply -> R3 ----
    int totProbe = N0 * 7;
    int Gp = (totProbe + 255) / 256;
    int chunkP = (Gp + 7) / 8;
    init_probe<<<8 * chunkP, 256, 0, stream>>>(totProbe, chunkP, c0, bm0,
                                               hk0, hv0, CAP0 - 1, pairs0, pcount, CAPP);
    init_center<<<(N0 * 64 + 255) / 256, 256, 0, stream>>>(N0, F0, Winit, R3);
    init_apply<<<(CAPP * 64) / 256, 256, 0, stream>>>(pairs0, pcount, CAPP, F0, Winit, R3);

    // ---- down1: R3 -> R1 raw; stats S0 ----
    hipMemsetAsync(R1, 0, (size_t)N1 * 64 * 4, stream);
    pair_gemm<64, 64, 0><<<8 * CH_D12, 256, 0, stream>>>(
        R3, nullptr, Wd1, R1, rbD1, cntD1, CAP_D1, CH_D12, 8 * CH_D12, 64, 1,
        nullptr, nullptr);
    bnstats(R1, N1, 64, gd1, bd1, 0);

    // ---- level-1 block 1 ----
    sub64(R1, W11a, R2, 0);
    bnstats(R2, N1, 64, g11, b11, 1);
    sub64(R2, W11b, R3, 1);
    add_lrelu_bn<<<(N1 * 16 + 255) / 256, 256, 0, stream>>>(
        (const float4*)R3, (const float4*)R1, (float4*)R2, N1 * 16, 15, scb, shb);  // R2 = x1
    // ---- level-1 block 2 ----
    sub64(R2, W12a, R3, -1);
    bnstats(R3, N1, 64, g12, b12, 2);
    sub64(R3, W12b, R1, 2);
    // x1' = lrelu(R1 + R2) fused into down2 staging

    // ---- down2 (fused residual add): lrelu(R1+R2) -> R3 raw [N2,128]; stats S3 ----
    hipMemsetAsync(R3, 0, (size_t)N2 * 128 * 4, stream);
    pair_gemm<64, 64, 2><<<8 * CH_D12, 256, 0, stream>>>(
        R1, R2, Wd2, R3, rbD2, cntD2, CAP_D2, CH_D12, 8 * CH_D12, 128, 2,
        nullptr, nullptr);
    bnstats(R3, N2, 128, gd2, bd2, 3);

    // ---- level-2 block 1 ----
    sub128(R3, W21a, R1, 3);
    bnstats(R1, N2, 128, g21, b21, 4);
    sub128(R1, W21b, R2, 4);
    add_lrelu_bn<<<(N2 * 32 + 255) / 256, 256, 0, stream>>>(
        (const float4*)R2, (const float4*)R3, (float4*)R1, N2 * 32, 31,
        scb + 3 * 128, shb + 3 * 128);                                              // R1 = x2
    // ---- level-2 block 2 ----
    sub128(R1, W22a, R2, -1);
    bnstats(R2, N2, 128, g22, b22, 5);
    sub128(R2, W22b, R3, 5);
    // x2' = lrelu(R3 + R1) fused into down3 staging

    // ---- down3 (fused residual add): lrelu(R3+R1) -> R2 raw [N3,64]; stats S6 ----
    hipMemsetAsync(R2, 0, (size_t)N3 * 64 * 4, stream);
    pair_gemm32<128, 16, 2><<<64 * CH_D3, 256, 0, stream>>>(
        R3, R1, Wd3, R2, rbD3, cntD3, CAP_D3, CH_D3, 64 * CH_D3, 64, 2,
        nullptr, nullptr);
    bnstats(R2, N3, 64, gd3, bd3, 6);

    // ---- fused tail: convd4 + BN(gd4) + scatter + head ----
    tail_kernel<<<N4, 64, 0, stream>>>(N4, c4, R2, Wd4, x4, hk3, hv3, CAP3 - 1,
                                       scb + 6 * 128, shb + 6 * 128, gd4, bd4,
                                       W2, b2, W3, b3, done, (float*)d_out);
}

// Round 13
// 1094.617 us; speedup vs baseline: 1.4293x; 1.4293x over previous
//
#include <hip/hip_runtime.h>

#define LEAKF (1.0f/3.0f)
#define BN_EPS 1e-4f

// ---------------- hash table (open addressing, linear probe) ----------------
__device__ __forceinline__ unsigned hmix(int key) {
    unsigned h = (unsigned)key * 2654435761u;
    h ^= h >> 15;
    return h;
}

__device__ __forceinline__ int hlookup(const int* __restrict__ hk,
                                       const int* __restrict__ hv,
                                       int mask, int key) {
    unsigned h = hmix(key) & (unsigned)mask;
    while (true) {
        int k = hk[h];
        if (k == key) return hv[h];
        if (k == -1) return -1;
        h = (h + 1) & (unsigned)mask;
    }
}

__device__ __forceinline__ float bnl(float v, float s, float h) {
    v = v * s + h;
    return v > 0.f ? v : v * LEAKF;
}

// ---------------- fused hash + bitmap build (4 segments) ----------------
__global__ __launch_bounds__(256) void build_hash_bm_all(
    int B0, int B1, int B2,
    int N0, const int* __restrict__ c0, int* __restrict__ hk0, int* __restrict__ hv0,
    int m0, unsigned* __restrict__ bm0,
    int N1, const int* __restrict__ c1, int* __restrict__ hk1, int* __restrict__ hv1,
    int m1, unsigned* __restrict__ bm1,
    int N2, const int* __restrict__ c2, int* __restrict__ hk2, int* __restrict__ hv2,
    int m2, unsigned* __restrict__ bm2,
    int N3, const int* __restrict__ c3, int* __restrict__ hk3, int* __restrict__ hv3,
    int m3) {
    const int* coords; int* hk; int* hv; unsigned* bm; int mask, S, N, i;
    int b = blockIdx.x;
    if (b < B0)           { coords = c0; hk = hk0; hv = hv0; bm = bm0; mask = m0; S = 512; N = N0; i = b * 256 + threadIdx.x; }
    else if (b < B0 + B1) { coords = c1; hk = hk1; hv = hv1; bm = bm1; mask = m1; S = 256; N = N1; i = (b - B0) * 256 + threadIdx.x; }
    else if (b < B0 + B1 + B2) { coords = c2; hk = hk2; hv = hv2; bm = bm2; mask = m2; S = 128; N = N2; i = (b - B0 - B1) * 256 + threadIdx.x; }
    else                  { coords = c3; hk = hk3; hv = hv3; bm = nullptr; mask = m3; S = 32; N = N3; i = (b - B0 - B1 - B2) * 256 + threadIdx.x; }
    if (i >= N) return;
    int key = (coords[3 * i] * S + coords[3 * i + 1]) * S + coords[3 * i + 2];
    if (bm) atomicOr(&bm[key >> 5], 1u << (key & 31));
    unsigned h = hmix(key) & (unsigned)mask;
    while (true) {
        int old = atomicCAS(&hk[h], -1, key);
        if (old == -1 || old == key) { hv[h] = i; break; }
        h = (h + 1) & (unsigned)mask;
    }
}

// ---------------- bitmap-based submanifold rulebook (2 segments) ----------------
__global__ __launch_bounds__(256) void rb_sub_bm(
    int B1,
    int N1, const int* __restrict__ c1, const unsigned* __restrict__ bm1,
    const int* __restrict__ hk1, const int* __restrict__ hv1, int m1,
    int2* __restrict__ rb1, int* __restrict__ cnt1, int cap1,
    int N2, const int* __restrict__ c2, const unsigned* __restrict__ bm2,
    const int* __restrict__ hk2, const int* __restrict__ hv2, int m2,
    int2* __restrict__ rb2, int* __restrict__ cnt2, int cap2) {
    __shared__ int lcnt[27];
    __shared__ int lbase[27];
    int tid = threadIdx.x;
    if (tid < 27) lcnt[tid] = 0;
    __syncthreads();
    const int* coords; const unsigned* bm; const int* hk; const int* hv;
    int mask, S, N, t; int2* pairs; int* counts; int cap;
    if (blockIdx.x < B1) {
        coords = c1; bm = bm1; hk = hk1; hv = hv1; mask = m1; S = 256; N = N1;
        pairs = rb1; counts = cnt1; cap = cap1; t = blockIdx.x * 256 + tid;
    } else {
        coords = c2; bm = bm2; hk = hk2; hv = hv2; mask = m2; S = 128; N = N2;
        pairs = rb2; counts = cnt2; cap = cap2; t = (blockIdx.x - B1) * 256 + tid;
    }
    unsigned bits = 0;
    int m = 0, kmin = 0, z = 0, dx = 0, dy = 0;
    int rk[3], ix[3];
    if (t < N * 9) {
        m = t / 9;
        int od = t - m * 9;
        dx = od / 3 - 1;
        dy = od - (od / 3) * 3 - 1;
        int x = coords[3 * m] + dx;
        int y = coords[3 * m + 1] + dy;
        z = coords[3 * m + 2];
        if ((unsigned)x < (unsigned)S && (unsigned)y < (unsigned)S) {
            int zmin = z - 1 < 0 ? 0 : z - 1;
            int zmax = z + 1 > S - 1 ? S - 1 : z + 1;
            kmin = (x * S + y) * S + zmin;
            int wi = kmin >> 5, sh = kmin & 31, nb = zmax - zmin + 1;
            unsigned long long w =
                ((unsigned long long)bm[wi + 1] << 32) | (unsigned long long)bm[wi];
            bits = (unsigned)((w >> sh) & ((1u << nb) - 1u));
            if (dx == 0 && dy == 0) bits &= ~(1u << (z - zmin));  // drop center
            unsigned tmp = bits;
            int nf = 0;
            while (tmp) {
                int bb = __ffs(tmp) - 1;
                tmp &= tmp - 1;
                ix[nf] = hlookup(hk, hv, mask, kmin + bb);
                int dz = (kmin & (S - 1)) + bb - z;
                int k = (dx + 1) * 9 + (dy + 1) * 3 + (dz + 1);
                rk[nf] = atomicAdd(&lcnt[k], 1);
                nf++;
            }
        }
    }
    __syncthreads();
    if (tid < 27 && lcnt[tid] > 0) lbase[tid] = atomicAdd(&counts[tid], lcnt[tid]);
    __syncthreads();
    {
        unsigned tmp = bits;
        int j = 0;
        while (tmp) {
            int bb = __ffs(tmp) - 1;
            tmp &= tmp - 1;
            int dz = (kmin & (S - 1)) + bb - z;
            int k = (dx + 1) * 9 + (dy + 1) * 3 + (dz + 1);
            int p = lbase[k] + rk[j];
            if (p < cap) pairs[(size_t)k * cap + p] = make_int2(m, ix[j]);
            j++;
        }
    }
}

// ---------------- fused down-conv rulebooks (3 segments) ----------------
__global__ __launch_bounds__(256) void rb_down_all(
    int B1, int B2,
    int N0, const int* __restrict__ c0, const int* __restrict__ hk1,
    const int* __restrict__ hv1, int m1, int2* __restrict__ rbD1,
    int* __restrict__ cntD1, int capD1,
    int N1, const int* __restrict__ c1, const int* __restrict__ hk2,
    const int* __restrict__ hv2, int m2, int2* __restrict__ rbD2,
    int* __restrict__ cntD2, int capD2,
    int N2, const int* __restrict__ c2, const int* __restrict__ hk3,
    const int* __restrict__ hv3, int m3, int2* __restrict__ rbD3,
    int* __restrict__ cntD3, int capD3) {
    __shared__ int lcnt[64];
    __shared__ int lbase[64];
    int tid = threadIdx.x;
    const int* cin; const int* hk; const int* hv;
    int mask, Sout, s, Nin, i; int2* pairs; int* counts; int cap;
    int b = blockIdx.x;
    if (b < B1) {
        cin = c0; hk = hk1; hv = hv1; mask = m1; Sout = 256; s = 2; Nin = N0;
        pairs = rbD1; counts = cntD1; cap = capD1; i = b * 256 + tid;
    } else if (b < B1 + B2) {
        cin = c1; hk = hk2; hv = hv2; mask = m2; Sout = 128; s = 2; Nin = N1;
        pairs = rbD2; counts = cntD2; cap = capD2; i = (b - B1) * 256 + tid;
    } else {
        cin = c2; hk = hk3; hv = hv3; mask = m3; Sout = 32; s = 4; Nin = N2;
        pairs = rbD3; counts = cntD3; cap = capD3; i = (b - B1 - B2) * 256 + tid;
    }
    int K3 = s * s * s;
    if (tid < K3) lcnt[tid] = 0;
    __syncthreads();
    int k = -1, m = -1, rank = 0;
    if (i < Nin) {
        int x = cin[3 * i], y = cin[3 * i + 1], z = cin[3 * i + 2];
        k = ((x % s) * s + (y % s)) * s + (z % s);
        int key = ((x / s) * Sout + (y / s)) * Sout + (z / s);
        m = hlookup(hk, hv, mask, key);
        rank = atomicAdd(&lcnt[k], 1);
    }
    __syncthreads();
    if (tid < K3 && lcnt[tid] > 0) lbase[tid] = atomicAdd(&counts[tid], lcnt[tid]);
    __syncthreads();
    if (i < Nin) {
        int p = lbase[k] + rank;
        if (p < cap) pairs[(size_t)k * cap + p] = make_int2(m, i);
    }
}

// ---- initial 7^3 conv probe: thread per (site,dx); 7 independent dy window loads ----
__global__ __launch_bounds__(256) void init_probe(
    int total, int chunk, const int* __restrict__ c0, const unsigned* __restrict__ bm,
    const int* __restrict__ hk, const int* __restrict__ hv, int mask,
    int2* __restrict__ pairs, int* __restrict__ pcount, int cap) {
    __shared__ int lcnt, lbase;
    int tid = threadIdx.x;
    if (tid == 0) lcnt = 0;
    __syncthreads();
    int b = blockIdx.x;
    int nb = (b & 7) * chunk + (b >> 3);
    int t = nb * 256 + tid;         // t indexes (site, dx); total = N0*7
    unsigned bitsArr[7];
    int kminArr[7];
#pragma unroll
    for (int j = 0; j < 7; j++) { bitsArr[j] = 0; kminArr[j] = 0; }
    int m = -1, z = 0, dx = 0, rank = 0, found = 0;
    if (t < total) {
        m = t / 7;
        dx = t - m * 7 - 3;
        int x = c0[3 * m] + dx;
        int cy = c0[3 * m + 1];
        z = c0[3 * m + 2];
        if ((unsigned)x < 512u) {
            int zmin = z - 3 < 0 ? 0 : z - 3;
            int zmax = z + 3 > 511 ? 511 : z + 3;
            int nbits = zmax - zmin + 1;
#pragma unroll
            for (int j = 0; j < 7; j++) {
                int y = cy + j - 3;
                if ((unsigned)y < 512u) {
                    int kmin = (x * 512 + y) * 512 + zmin;
                    kminArr[j] = kmin;
                    int wi = kmin >> 5, sh = kmin & 31;
                    unsigned long long w =
                        ((unsigned long long)bm[wi + 1] << 32) | (unsigned long long)bm[wi];
                    unsigned bits = (unsigned)((w >> sh) & ((1u << nbits) - 1u));
                    if (dx == 0 && j == 3) bits &= ~(1u << (z - zmin));  // drop center
                    bitsArr[j] = bits;
                    found += __popc(bits);
                }
            }
        }
    }
    if (found) rank = atomicAdd(&lcnt, found);
    __syncthreads();
    if (tid == 0 && lcnt > 0) lbase = atomicAdd(pcount, lcnt);
    __syncthreads();
    if (found) {
        int p = lbase + rank;
#pragma unroll
        for (int j = 0; j < 7; j++) {
            unsigned bits = bitsArr[j];
            while (bits) {
                int b2 = __ffs(bits) - 1;
                bits &= bits - 1;
                int nkey = kminArr[j] + b2;
                int idx = hlookup(hk, hv, mask, nkey);
                int dz = (kminArr[j] & 511) + b2 - z;
                int k = (dx + 3) * 49 + j * 7 + (dz + 3);
                if (p < cap) pairs[p] = make_int2(m, idx | (k << 17));
                p++;
            }
        }
    }
}

__global__ __launch_bounds__(256) void init_center(
    int N0, const float* __restrict__ f0, const float* __restrict__ W,
    float* __restrict__ out) {
    int t = blockIdx.x * 256 + threadIdx.x;
    if (t >= N0 * 64) return;
    int m = t >> 6, co = t & 63;
    out[t] = f0[m] * W[171 * 64 + co];
}

__global__ __launch_bounds__(256) void init_apply(
    const int2* __restrict__ pairs, const int* __restrict__ pcount, int cap,
    const float* __restrict__ f0, const float* __restrict__ W,
    float* __restrict__ out) {
    int P = min(*pcount, cap);
    int t = blockIdx.x * 256 + threadIdx.x;
    if (t >= P * 64) return;
    int p = t >> 6, co = t & 63;
    int2 pr = pairs[p];
    int idx = pr.y & 0x1FFFF, k = pr.y >> 17;
    atomicAdd(&out[(size_t)pr.x * 64 + co], f0[idx] * W[k * 64 + co]);
}

// ---------------- center GEMM: thread owns 2 cos (co, co+32) ----------------
template <int C, int TS, bool BNF>
__global__ __launch_bounds__(256) void center_gemm(
    int N, const float* __restrict__ inF, const float* __restrict__ Wc,
    float* __restrict__ out, const float* __restrict__ scp,
    const float* __restrict__ shp) {
    constexpr int C4 = C / 4;
    constexpr int SP = TS / 8;
    __shared__ float sW[C * 64];
    __shared__ float4 sRow[TS * C4];
    int tid = threadIdx.x;
    int t0 = blockIdx.x * TS;
    int co0 = blockIdx.y << 6;
    for (int e = tid; e < C * 16; e += 256) {
        int ci = e >> 4, c4 = e & 15;
        ((float4*)sW)[e] = *(const float4*)(Wc + (size_t)ci * C + co0 + c4 * 4);
    }
    for (int e = tid; e < TS * C4; e += 256) {
        int p = e / C4, c4 = e - p * C4;
        float4 v = make_float4(0.f, 0.f, 0.f, 0.f);
        if (t0 + p < N) {
            v = ((const float4*)inF)[(size_t)(t0 + p) * C4 + c4];
            if (BNF) {
                float4 s4 = ((const float4*)scp)[c4];
                float4 h4 = ((const float4*)shp)[c4];
                v.x = bnl(v.x, s4.x, h4.x);
                v.y = bnl(v.y, s4.y, h4.y);
                v.z = bnl(v.z, s4.z, h4.z);
                v.w = bnl(v.w, s4.w, h4.w);
            }
        }
        sRow[e] = v;
    }
    __syncthreads();
    int co = tid & 31, sg = tid >> 5;
    float accA[SP], accB[SP];
#pragma unroll
    for (int j = 0; j < SP; j++) { accA[j] = 0.f; accB[j] = 0.f; }
    for (int c4 = 0; c4 < C4; c4++) {
        float a0 = sW[(c4 * 4 + 0) * 64 + co];
        float a1 = sW[(c4 * 4 + 1) * 64 + co];
        float a2 = sW[(c4 * 4 + 2) * 64 + co];
        float a3 = sW[(c4 * 4 + 3) * 64 + co];
        float b0 = sW[(c4 * 4 + 0) * 64 + co + 32];
        float b1 = sW[(c4 * 4 + 1) * 64 + co + 32];
        float b2 = sW[(c4 * 4 + 2) * 64 + co + 32];
        float b3 = sW[(c4 * 4 + 3) * 64 + co + 32];
#pragma unroll
        for (int j = 0; j < SP; j++) {
            float4 r = sRow[(sg * SP + j) * C4 + c4];
            accA[j] += r.x * a0 + r.y * a1 + r.z * a2 + r.w * a3;
            accB[j] += r.x * b0 + r.y * b1 + r.z * b2 + r.w * b3;
        }
    }
#pragma unroll
    for (int j = 0; j < SP; j++) {
        int p = sg * SP + j;
        if (t0 + p < N) {
            out[(size_t)(t0 + p) * C + co0 + co] = accA[j];
            out[(size_t)(t0 + p) * C + co0 + co + 32] = accB[j];
        }
    }
}

// ---- pair GEMM; XCD-swizzled; in-block loop over co-slabs (rows gathered ONCE).
// MODE: 0=raw, 1=bn+lrelu, 2=lrelu(inF+inF2). ----
template <int CIN, int P, int MODE>
__global__ __launch_bounds__(256) void pair_gemm(
    const float* __restrict__ inF, const float* __restrict__ inF2,
    const float* __restrict__ W, float* __restrict__ out,
    const int2* __restrict__ pairs, const int* __restrict__ counts,
    int cap, int chunksPerK, int totalNb, int COUT, int nslab,
    const float* __restrict__ scp, const float* __restrict__ shp) {
    constexpr int C4 = CIN / 4;
    constexpr int SP = P / 8;
    __shared__ float sW[CIN * 64];
    __shared__ float4 sRow[P * C4];
    __shared__ int sM[P];
    __shared__ int sIdx[P];
    int b = blockIdx.x;
    int nb = (b & 7) * (gridDim.x >> 3) + (b >> 3);
    if (nb >= totalNb) return;
    int k = nb / chunksPerK;
    int chunk = nb - k * chunksPerK;
    int cnt = min(counts[k], cap);
    int base = chunk * P;
    if (base >= cnt) return;
    int Pact = min(P, cnt - base);
    int tid = threadIdx.x;
    if (tid < P) {
        if (tid < Pact) {
            int2 pr = pairs[(size_t)k * cap + base + tid];
            sM[tid] = pr.x;
            sIdx[tid] = pr.y;
        } else {
            sM[tid] = -1;
            sIdx[tid] = 0;
        }
    }
    __syncthreads();
    int co = tid & 31, sg = tid >> 5;
    for (int s = 0; s < nslab; s++) {
        int co0 = s << 6;
        if (s > 0) __syncthreads();  // protect sW from prior slab's readers
        const float* gW = W + (size_t)k * CIN * COUT + co0;
        for (int e = tid; e < CIN * 16; e += 256) {
            int ci = e >> 4, c4 = e & 15;
            ((float4*)sW)[e] = *(const float4*)(gW + (size_t)ci * COUT + c4 * 4);
        }
        if (s == 0) {
            for (int e = tid; e < P * C4; e += 256) {
                int p = e / C4, c4 = e - p * C4;
                float4 v = make_float4(0.f, 0.f, 0.f, 0.f);
                if (p < Pact) {
                    v = ((const float4*)inF)[(size_t)sIdx[p] * C4 + c4];
                    if (MODE == 1) {
                        float4 s4 = ((const float4*)scp)[c4];
                        float4 h4 = ((const float4*)shp)[c4];
                        v.x = bnl(v.x, s4.x, h4.x);
                        v.y = bnl(v.y, s4.y, h4.y);
                        v.z = bnl(v.z, s4.z, h4.z);
                        v.w = bnl(v.w, s4.w, h4.w);
                    } else if (MODE == 2) {
                        float4 u = ((const float4*)inF2)[(size_t)sIdx[p] * C4 + c4];
                        v.x += u.x; v.y += u.y; v.z += u.z; v.w += u.w;
                        v.x = v.x > 0.f ? v.x : v.x * LEAKF;
                        v.y = v.y > 0.f ? v.y : v.y * LEAKF;
                        v.z = v.z > 0.f ? v.z : v.z * LEAKF;
                        v.w = v.w > 0.f ? v.w : v.w * LEAKF;
                    }
                }
                sRow[e] = v;
            }
        }
        __syncthreads();
        float accA[SP], accB[SP];
#pragma unroll
        for (int j = 0; j < SP; j++) { accA[j] = 0.f; accB[j] = 0.f; }
        for (int c4 = 0; c4 < C4; c4++) {
            float a0 = sW[(c4 * 4 + 0) * 64 + co];
            float a1 = sW[(c4 * 4 + 1) * 64 + co];
            float a2 = sW[(c4 * 4 + 2) * 64 + co];
            float a3 = sW[(c4 * 4 + 3) * 64 + co];
            float b0 = sW[(c4 * 4 + 0) * 64 + co + 32];
            float b1 = sW[(c4 * 4 + 1) * 64 + co + 32];
            float b2 = sW[(c4 * 4 + 2) * 64 + co + 32];
            float b3 = sW[(c4 * 4 + 3) * 64 + co + 32];
#pragma unroll
            for (int j = 0; j < SP; j++) {
                float4 r = sRow[(sg * SP + j) * C4 + c4];
                accA[j] += r.x * a0 + r.y * a1 + r.z * a2 + r.w * a3;
                accB[j] += r.x * b0 + r.y * b1 + r.z * b2 + r.w * b3;
            }
        }
#pragma unroll
        for (int j = 0; j < SP; j++) {
            int p = sg * SP + j;
            if (p < Pact) {
                atomicAdd(&out[(size_t)sM[p] * COUT + co0 + co], accA[j]);
                atomicAdd(&out[(size_t)sM[p] * COUT + co0 + co + 32], accB[j]);
            }
        }
    }
}

// ---------------- batchnorm: register-accum reduce + last-block finalize ----------------
__global__ __launch_bounds__(256) void bn_reduce_fin(
    const float4* __restrict__ X4, int total4, int B4, int C, int Cmask, float invN,
    const float* __restrict__ g, const float* __restrict__ b,
    float* __restrict__ sums, int* __restrict__ done,
    float* __restrict__ sc, float* __restrict__ sh) {
    __shared__ float sS[128];
    __shared__ float sQ[128];
    __shared__ int isLast;
    int tid = threadIdx.x;
    if (tid < C) { sS[tid] = 0.f; sQ[tid] = 0.f; }
    __syncthreads();
    int base4 = blockIdx.x * B4;
    int end4 = min(base4 + B4, total4);
    float s0 = 0.f, s1 = 0.f, s2 = 0.f, s3 = 0.f;
    float q0 = 0.f, q1 = 0.f, q2 = 0.f, q3 = 0.f;
    for (int e4 = base4 + tid; e4 < end4; e4 += 256) {
        float4 v = X4[e4];
        s0 += v.x; q0 += v.x * v.x;
        s1 += v.y; q1 += v.y * v.y;
        s2 += v.z; q2 += v.z * v.z;
        s3 += v.w; q3 += v.w * v.w;
    }
    int c0 = (4 * (base4 + tid)) & Cmask;
    atomicAdd(&sS[c0], s0);               atomicAdd(&sQ[c0], q0);
    atomicAdd(&sS[(c0 + 1) & Cmask], s1); atomicAdd(&sQ[(c0 + 1) & Cmask], q1);
    atomicAdd(&sS[(c0 + 2) & Cmask], s2); atomicAdd(&sQ[(c0 + 2) & Cmask], q2);
    atomicAdd(&sS[(c0 + 3) & Cmask], s3); atomicAdd(&sQ[(c0 + 3) & Cmask], q3);
    __syncthreads();
    if (tid < C) {
        atomicAdd(&sums[tid], sS[tid]);
        atomicAdd(&sums[128 + tid], sQ[tid]);
    }
    __syncthreads();
    if (tid == 0) {
        __threadfence();
        int t = atomicAdd(done, 1);
        isLast = (t == (int)gridDim.x - 1);
    }
    __syncthreads();
    if (isLast) {
        if (tid < C) {
            float v1 = atomicAdd(&sums[tid], 0.0f);
            float v2 = atomicAdd(&sums[128 + tid], 0.0f);
            float mean = v1 * invN;
            float var = v2 * invN - mean * mean;
            float s = g[tid] / sqrtf(var + BN_EPS);
            sc[tid] = s;
            sh[tid] = b[tid] - mean * s;
            sums[tid] = 0.f;
            sums[128 + tid] = 0.f;
        }
        if (tid == 0) *done = 0;
    }
}

// out = lrelu(A + bnl(X))   (float4)
__global__ __launch_bounds__(256) void add_lrelu_bn(const float4* __restrict__ A,
                                                    const float4* __restrict__ X,
                                                    float4* __restrict__ Y, int total4,
                                                    int C4mask,
                                                    const float* __restrict__ scp,
                                                    const float* __restrict__ shp) {
    int e = blockIdx.x * 256 + threadIdx.x;
    if (e >= total4) return;
    int c4 = e & C4mask;
    float4 s4 = ((const float4*)scp)[c4];
    float4 h4 = ((const float4*)shp)[c4];
    float4 a = A[e], x = X[e], v;
    v.x = a.x + bnl(x.x, s4.x, h4.x);
    v.y = a.y + bnl(x.y, s4.y, h4.y);
    v.z = a.z + bnl(x.z, s4.z, h4.z);
    v.w = a.w + bnl(x.w, s4.w, h4.w);
    v.x = v.x > 0.f ? v.x : v.x * LEAKF;
    v.y = v.y > 0.f ? v.y : v.y * LEAKF;
    v.z = v.z > 0.f ? v.z : v.z * LEAKF;
    v.w = v.w > 0.f ? v.w : v.w * LEAKF;
    Y[e] = v;
}

// ---- fused tail: convd4 (bnl on input) -> last-block BN(gd4) + scatter + head ----
__global__ __launch_bounds__(64) void tail_kernel(
    int M, const int* __restrict__ oc, const float* __restrict__ x3,
    const float* __restrict__ W, float* __restrict__ x4,
    const int* __restrict__ hk, const int* __restrict__ hv, int mask,
    const float* __restrict__ scp, const float* __restrict__ shp,
    const float* __restrict__ g4, const float* __restrict__ b4,
    const float* __restrict__ W2, const float* __restrict__ b2,
    const float* __restrict__ W3, const float* __restrict__ b3,
    int* __restrict__ ticket, float* __restrict__ out) {
    __shared__ int sIdx[64];
    __shared__ int sK[64];
    __shared__ int sCount;
    __shared__ int isLast;
    __shared__ float sDense[1024];
    __shared__ float sS[2], sQ[2], ssc[2], ssh[2];
    int m = blockIdx.x, tid = threadIdx.x;
    int cx = oc[3 * m], cy = oc[3 * m + 1], cz = oc[3 * m + 2];
    if (tid == 0) sCount = 0;
    __syncthreads();
    {
        int k = tid;
        int a = k >> 4, b = (k >> 2) & 3, c = k & 3;
        int x = cx * 4 + a, y = cy * 4 + b, z = cz * 4 + c;
        int key = (x * 32 + y) * 32 + z;
        int idx = hlookup(hk, hv, mask, key);
        if (idx >= 0) { int p = atomicAdd(&sCount, 1); sIdx[p] = idx; sK[p] = k; }
    }
    __syncthreads();
    int cnt = sCount;
    float s = scp[tid], h = shp[tid];
    float a0 = 0.f, a1 = 0.f;
    for (int j = 0; j < cnt; j++) {
        int idx = sIdx[j], k = sK[j];
        float f = bnl(x3[(size_t)idx * 64 + tid], s, h);
        const float* wk = W + ((size_t)k * 64 + tid) * 2;
        a0 += f * wk[0];
        a1 += f * wk[1];
    }
    for (int o = 32; o > 0; o >>= 1) {
        a0 += __shfl_down(a0, o);
        a1 += __shfl_down(a1, o);
    }
    if (tid == 0) { x4[2 * m] = a0; x4[2 * m + 1] = a1; }
    __threadfence();
    if (tid == 0) {
        int t = atomicAdd(ticket, 1);
        isLast = (t == (int)gridDim.x - 1);
    }
    __syncthreads();
    if (!isLast) return;
    if (tid < 2) { sS[tid] = 0.f; sQ[tid] = 0.f; }
    for (int i = tid; i < 1024; i += 64) sDense[i] = 0.f;
    __syncthreads();
    float ls = 0.f, lq = 0.f;
    for (int i = tid; i < 2 * M; i += 64) {
        float v = atomicAdd(&x4[i], 0.0f);
        ls += v; lq += v * v;
    }
    atomicAdd(&sS[tid & 1], ls);
    atomicAdd(&sQ[tid & 1], lq);
    __syncthreads();
    if (tid < 2) {
        float mean = sS[tid] / (float)M;
        float var = sQ[tid] / (float)M - mean * mean;
        float sc = g4[tid] / sqrtf(var + BN_EPS);
        ssc[tid] = sc;
        ssh[tid] = b4[tid] - mean * sc;
    }
    __syncthreads();
    for (int i = tid; i < 2 * M; i += 64) {
        int mm = i >> 1, co = i & 1;
        float v = atomicAdd(&x4[i], 0.0f) * ssc[co] + ssh[co];
        v = v > 0.f ? v : v * LEAKF;
        int key = (oc[3 * mm] * 8 + oc[3 * mm + 1]) * 8 + oc[3 * mm + 2];
        sDense[key * 2 + co] = v;
    }
    __syncthreads();
    float h0 = 0.f, h1 = 0.f;
    for (int j = tid; j < 1024; j += 64) {
        int co = j >> 9, k = j & 511;
        float f = sDense[k * 2 + co];
        h0 += f * W2[2 * j];
        h1 += f * W2[2 * j + 1];
    }
    for (int o = 32; o > 0; o >>= 1) {
        h0 += __shfl_down(h0, o);
        h1 += __shfl_down(h1, o);
    }
    if (tid == 0) {
        float v0 = h0 + b2[0];
        float v1 = h1 + b2[1];
        v0 = v0 > 0.f ? v0 : expm1f(v0);
        v1 = v1 > 0.f ? v1 : expm1f(v1);
        float z = v0 * W3[0] + v1 * W3[1] + b3[0];
        out[0] = 1.f / (1.f + expf(-z));
    }
}

// ---------------- host ----------------
extern "C" void kernel_launch(void* const* d_in, const int* in_sizes, int n_in,
                              void* d_out, int out_size, void* d_ws, size_t ws_size,
                              hipStream_t stream) {
    const float* F0    = (const float*)d_in[0];
    const float* Winit = (const float*)d_in[1];
    const float* Wd1   = (const float*)d_in[2];
    const float* gd1   = (const float*)d_in[3];
    const float* bd1   = (const float*)d_in[4];
    const float* W11a  = (const float*)d_in[5];
    const float* g11   = (const float*)d_in[6];
    const float* b11   = (const float*)d_in[7];
    const float* W11b  = (const float*)d_in[8];
    const float* W12a  = (const float*)d_in[9];
    const float* g12   = (const float*)d_in[10];
    const float* b12   = (const float*)d_in[11];
    const float* W12b  = (const float*)d_in[12];
    const float* Wd2   = (const float*)d_in[13];
    const float* gd2   = (const float*)d_in[14];
    const float* bd2   = (const float*)d_in[15];
    const float* W21a  = (const float*)d_in[16];
    const float* g21   = (const float*)d_in[17];
    const float* b21   = (const float*)d_in[18];
    const float* W21b  = (const float*)d_in[19];
    const float* W22a  = (const float*)d_in[20];
    const float* g22   = (const float*)d_in[21];
    const float* b22   = (const float*)d_in[22];
    const float* W22b  = (const float*)d_in[23];
    const float* Wd3   = (const float*)d_in[24];
    const float* gd3   = (const float*)d_in[25];
    const float* bd3   = (const float*)d_in[26];
    const float* Wd4   = (const float*)d_in[27];
    const float* gd4   = (const float*)d_in[28];
    const float* bd4   = (const float*)d_in[29];
    const float* W2    = (const float*)d_in[30];
    const float* b2    = (const float*)d_in[31];
    const float* W3    = (const float*)d_in[32];
    const float* b3    = (const float*)d_in[33];
    const int* c0 = (const int*)d_in[34];
    const int* c1 = (const int*)d_in[35];
    const int* c2 = (const int*)d_in[36];
    const int* c3 = (const int*)d_in[37];
    const int* c4 = (const int*)d_in[38];
    int N0 = in_sizes[34] / 3, N1 = in_sizes[35] / 3, N2 = in_sizes[36] / 3;
    int N3 = in_sizes[37] / 3, N4 = in_sizes[38] / 3;

    // ---- workspace layout ----
    char* base = (char*)d_ws;
    size_t off = 0;
    auto alloc = [&](size_t bytes) -> void* {
        void* p = base + off;
        off = (off + bytes + 255) & ~(size_t)255;
        return p;
    };
    const int CAP0 = 262144, CAP = 131072, CAP3 = 65536;
    size_t hs_off = off;
    int* hk0 = (int*)alloc((size_t)CAP0 * 4);
    int* hv0 = (int*)alloc((size_t)CAP0 * 4);
    int* hk1 = (int*)alloc((size_t)CAP * 4);
    int* hv1 = (int*)alloc((size_t)CAP * 4);
    int* hk2 = (int*)alloc((size_t)CAP * 4);
    int* hv2 = (int*)alloc((size_t)CAP * 4);
    int* hk3 = (int*)alloc((size_t)CAP3 * 4);
    int* hv3 = (int*)alloc((size_t)CAP3 * 4);
    size_t he_off = off;
    size_t zs_off = off;
    float* sums = (float*)alloc(256 * 4);
    float* scb = (float*)alloc(8 * 128 * 4);
    float* shb = (float*)alloc(8 * 128 * 4);
    float* x4 = (float*)alloc(1032 * 4);
    int* counts = (int*)alloc(136 * 4);
    unsigned* bm1 = (unsigned*)alloc((size_t)(524288 + 2) * 4);
    unsigned* bm2 = (unsigned*)alloc((size_t)(65536 + 2) * 4);
    size_t ze_off = off;
    int* cntS1 = counts, *cntS2 = counts + 27, *cntD1 = counts + 54, *cntD2 = counts + 62,
       * cntD3 = counts + 70;
    int* done = counts + 134;
    int* pcount = counts + 135;
    const int CAP_S1 = 1024, CAP_S2 = 4096, CAP_D1 = 8192, CAP_D2 = 8192, CAP_D3 = 1024;
    const int CAPP = 16384;
    int2* pairs0 = (int2*)alloc((size_t)CAPP * 8);
    int2* rbS1 = (int2*)alloc((size_t)27 * CAP_S1 * 8);
    int2* rbS2 = (int2*)alloc((size_t)27 * CAP_S2 * 8);
    int2* rbD1 = (int2*)alloc((size_t)8 * CAP_D1 * 8);
    int2* rbD2 = (int2*)alloc((size_t)8 * CAP_D2 * 8);
    int2* rbD3 = (int2*)alloc((size_t)64 * CAP_D3 * 8);
    size_t relems = (size_t)N0 * 64;
    if ((size_t)N2 * 128 > relems) relems = (size_t)N2 * 128;
    float* R1 = (float*)alloc(relems * 4);
    float* R2 = (float*)alloc(relems * 4);
    float* R3 = (float*)alloc(relems * 4);
    unsigned* bm0 = (unsigned*)R1;   // 16.8 MB, dead before down1

    // ---- consolidated init memsets ----
    hipMemsetAsync(base + hs_off, 0xFF, he_off - hs_off, stream);
    hipMemsetAsync(base + zs_off, 0x00, ze_off - zs_off, stream);
    hipMemsetAsync(bm0, 0x00, (size_t)(1 << 24) + 64, stream);

    int Bh0 = (N0 + 255) / 256, Bh1 = (N1 + 255) / 256, Bh2 = (N2 + 255) / 256,
        Bh3 = (N3 + 255) / 256;
    build_hash_bm_all<<<Bh0 + Bh1 + Bh2 + Bh3, 256, 0, stream>>>(
        Bh0, Bh1, Bh2,
        N0, c0, hk0, hv0, CAP0 - 1, bm0,
        N1, c1, hk1, hv1, CAP - 1, bm1,
        N2, c2, hk2, hv2, CAP - 1, bm2,
        N3, c3, hk3, hv3, CAP3 - 1);
    int Bs1 = (N1 * 9 + 255) / 256, Bs2 = (N2 * 9 + 255) / 256;
    rb_sub_bm<<<Bs1 + Bs2, 256, 0, stream>>>(
        Bs1,
        N1, c1, bm1, hk1, hv1, CAP - 1, rbS1, cntS1, CAP_S1,
        N2, c2, bm2, hk2, hv2, CAP - 1, rbS2, cntS2, CAP_S2);
    rb_down_all<<<Bh0 + Bh1 + Bh2, 256, 0, stream>>>(
        Bh0, Bh1,
        N0, c0, hk1, hv1, CAP - 1, rbD1, cntD1, CAP_D1,
        N1, c1, hk2, hv2, CAP - 1, rbD2, cntD2, CAP_D2,
        N2, c2, hk3, hv3, CAP3 - 1, rbD3, cntD3, CAP_D3);

    auto bnstats = [&](const float* X, int N, int C, const float* g, const float* b,
                       int slot) {
        int total4 = (N * C + 3) >> 2;
        int B4 = 32 * C;
        int grid = (total4 + B4 - 1) / B4;
        bn_reduce_fin<<<grid, 256, 0, stream>>>((const float4*)X, total4, B4, C, C - 1,
                                                1.0f / (float)N, g, b, sums, done,
                                                scb + slot * 128, shb + slot * 128);
    };
    const int CH_S1 = CAP_S1 / 64;    // 16  -> 432 blocks
    const int CH_S2 = CAP_S2 / 32;    // 128 -> 3456 blocks
    const int CH_D12 = CAP_D1 / 64;   // 128 -> 1024 blocks
    const int CH_D3 = CAP_D3 / 32;    // 32  -> 2048 blocks
    auto sub64 = [&](const float* X, const float* W, float* Y, int slot) {
        if (slot >= 0) {
            center_gemm<64, 64, true><<<dim3((N1 + 63) / 64, 1), 256, 0, stream>>>(
                N1, X, W + 13 * 64 * 64, Y, scb + slot * 128, shb + slot * 128);
            pair_gemm<64, 64, 1><<<27 * CH_S1, 256, 0, stream>>>(
                X, nullptr, W, Y, rbS1, cntS1, CAP_S1, CH_S1, 27 * CH_S1, 64, 1,
                scb + slot * 128, shb + slot * 128);
        } else {
            center_gemm<64, 64, false><<<dim3((N1 + 63) / 64, 1), 256, 0, stream>>>(
                N1, X, W + 13 * 64 * 64, Y, nullptr, nullptr);
            pair_gemm<64, 64, 0><<<27 * CH_S1, 256, 0, stream>>>(
                X, nullptr, W, Y, rbS1, cntS1, CAP_S1, CH_S1, 27 * CH_S1, 64, 1,
                nullptr, nullptr);
        }
    };
    auto sub128 = [&](const float* X, const float* W, float* Y, int slot) {
        if (slot >= 0) {
            center_gemm<128, 48, true><<<dim3((N2 + 47) / 48, 2), 256, 0, stream>>>(
                N2, X, W + 13 * 128 * 128, Y, scb + slot * 128, shb + slot * 128);
            pair_gemm<128, 32, 1><<<27 * CH_S2, 256, 0, stream>>>(
                X, nullptr, W, Y, rbS2, cntS2, CAP_S2, CH_S2, 27 * CH_S2, 128, 2,
                scb + slot * 128, shb + slot * 128);
        } else {
            center_gemm<128, 48, false><<<dim3((N2 + 47) / 48, 2), 256, 0, stream>>>(
                N2, X, W + 13 * 128 * 128, Y, nullptr, nullptr);
            pair_gemm<128, 32, 0><<<27 * CH_S2, 256, 0, stream>>>(
                X, nullptr, W, Y, rbS2, cntS2, CAP_S2, CH_S2, 27 * CH_S2, 128, 2,
                nullptr, nullptr);
        }
    };

    // ---- initial conv @512: (site,dx) probe / center / apply -> R3 ----
    int totProbe = N0 * 7;
    int Gp = (totProbe + 255) / 256;
    int chunkP = (Gp + 7) / 8;
    init_probe<<<8 * chunkP, 256, 0, stream>>>(totProbe, chunkP, c0, bm0,
                                               hk0, hv0, CAP0 - 1, pairs0, pcount, CAPP);
    init_center<<<(N0 * 64 + 255) / 256, 256, 0, stream>>>(N0, F0, Winit, R3);
    init_apply<<<(CAPP * 64) / 256, 256, 0, stream>>>(pairs0, pcount, CAPP, F0, Winit, R3);

    // ---- down1: R3 -> R1 raw; stats S0 ----
    hipMemsetAsync(R1, 0, (size_t)N1 * 64 * 4, stream);
    pair_gemm<64, 64, 0><<<8 * CH_D12, 256, 0, stream>>>(
        R3, nullptr, Wd1, R1, rbD1, cntD1, CAP_D1, CH_D12, 8 * CH_D12, 64, 1,
        nullptr, nullptr);
    bnstats(R1, N1, 64, gd1, bd1, 0);

    // ---- level-1 block 1 ----
    sub64(R1, W11a, R2, 0);
    bnstats(R2, N1, 64, g11, b11, 1);
    sub64(R2, W11b, R3, 1);
    add_lrelu_bn<<<(N1 * 16 + 255) / 256, 256, 0, stream>>>(
        (const float4*)R3, (const float4*)R1, (float4*)R2, N1 * 16, 15, scb, shb);  // R2 = x1
    // ---- level-1 block 2 ----
    sub64(R2, W12a, R3, -1);
    bnstats(R3, N1, 64, g12, b12, 2);
    sub64(R3, W12b, R1, 2);
    // x1' = lrelu(R1 + R2) fused into down2 staging

    // ---- down2 (fused residual add): lrelu(R1+R2) -> R3 raw [N2,128]; stats S3 ----
    hipMemsetAsync(R3, 0, (size_t)N2 * 128 * 4, stream);
    pair_gemm<64, 64, 2><<<8 * CH_D12, 256, 0, stream>>>(
        R1, R2, Wd2, R3, rbD2, cntD2, CAP_D2, CH_D12, 8 * CH_D12, 128, 2,
        nullptr, nullptr);
    bnstats(R3, N2, 128, gd2, bd2, 3);

    // ---- level-2 block 1 ----
    sub128(R3, W21a, R1, 3);
    bnstats(R1, N2, 128, g21, b21, 4);
    sub128(R1, W21b, R2, 4);
    add_lrelu_bn<<<(N2 * 32 + 255) / 256, 256, 0, stream>>>(
        (const float4*)R2, (const float4*)R3, (float4*)R1, N2 * 32, 31,
        scb + 3 * 128, shb + 3 * 128);                                              // R1 = x2
    // ---- level-2 block 2 ----
    sub128(R1, W22a, R2, -1);
    bnstats(R2, N2, 128, g22, b22, 5);
    sub128(R2, W22b, R3, 5);
    // x2' = lrelu(R3 + R1) fused into down3 staging

    // ---- down3 (fused residual add): lrelu(R3+R1) -> R2 raw [N3,64]; stats S6 ----
    hipMemsetAsync(R2, 0, (size_t)N3 * 64 * 4, stream);
    pair_gemm<128, 32, 2><<<64 * CH_D3, 256, 0, stream>>>(
        R3, R1, Wd3, R2, rbD3, cntD3, CAP_D3, CH_D3, 64 * CH_D3, 64, 1,
        nullptr, nullptr);
    bnstats(R2, N3, 64, gd3, bd3, 6);

    // ---- fused tail: convd4 + BN(gd4) + scatter + head ----
    tail_kernel<<<N4, 64, 0, stream>>>(N4, c4, R2, Wd4, x4, hk3, hv3, CAP3 - 1,
                                       scb + 6 * 128, shb + 6 * 128, gd4, bd4,
                                       W2, b2, W3, b3, done, (float*)d_out);
}